// Round 1
// baseline (190.081 us; speedup 1.0000x reference)
//
#include <hip/hip_runtime.h>
#include <hip/hip_bf16.h>

typedef __bf16 bf16_t;
typedef __bf16 bf16x8 __attribute__((ext_vector_type(8)));
typedef float f32x4 __attribute__((ext_vector_type(4)));
typedef unsigned short u16;

#define DEVI __device__ __forceinline__
#define MFMA16x16x32(A, B, C) __builtin_amdgcn_mfma_f32_16x16x32_bf16(A, B, C, 0, 0, 0)

DEVI void gload_lds16(const void* g, void* l) {
  __builtin_amdgcn_global_load_lds(
      (const __attribute__((address_space(1))) void*)g,
      (__attribute__((address_space(3))) void*)l, 16, 0, 0);
}

DEVI u16 bits_of(bf16_t x) { return __builtin_bit_cast(u16, x); }

// ---------------- fp32 -> bf16 conversion (vectorized) ----------------
__global__ void cvt_f32_bf16(const float4* __restrict__ in, ushort4* __restrict__ out, int n4) {
  int i = blockIdx.x * 256 + threadIdx.x;
  if (i < n4) {
    float4 v = in[i];
    ushort4 o;
    o.x = bits_of((bf16_t)v.x);
    o.y = bits_of((bf16_t)v.y);
    o.z = bits_of((bf16_t)v.z);
    o.w = bits_of((bf16_t)v.w);
    out[i] = o;
  }
}

// ---------------- GEMM: out[m][n] = sum_k A[m][k] * W[n][k] + bias[n] ----------------
// A: [M,1024] bf16 row-major; W: [1024,1024] bf16 row-major (rows = output features).
// 128x128 tile, BK=32, 4 waves (2x2 of 64x64), 16x16x32 bf16 MFMA, global_load_lds staging.
// OUT_KIND: 0 = bf16 output, 1 = f32 output.
template <int OUT_KIND>
__global__ __launch_bounds__(256, 3) void gemm_bt(
    const bf16_t* __restrict__ A,
    const bf16_t* __restrict__ W0, const bf16_t* __restrict__ W1, const bf16_t* __restrict__ W2,
    const float* __restrict__ b0, const float* __restrict__ b1, const float* __restrict__ b2,
    void* o0, void* o1, void* o2) {
  constexpr int K = 1024, N = 1024;
  const int z = blockIdx.z;
  const bf16_t* W = (z == 0) ? W0 : ((z == 1) ? W1 : W2);
  const float* bias = (z == 0) ? b0 : ((z == 1) ? b1 : b2);
  void* out = (z == 0) ? o0 : ((z == 1) ? o1 : o2);

  __shared__ bf16_t As[128 * 32];
  __shared__ bf16_t Bs[128 * 32];

  const int tid = threadIdx.x;
  const int wave = tid >> 6, lane = tid & 63;
  const int g = lane >> 4, l15 = lane & 15;
  const long m0 = (long)blockIdx.x * 128;
  const long n0 = (long)blockIdx.y * 128;

  const int srow = lane >> 2;        // 0..15 row within 16-row chunk
  const int scol = (lane & 3) * 8;   // elem offset (8 bf16 = 16B)

  const int wr = (wave >> 1) * 64;
  const int wc = (wave & 1) * 64;

  f32x4 acc[4][4] = {};

  for (int k0 = 0; k0 < K; k0 += 32) {
    __syncthreads();  // previous-iteration LDS reads done
#pragma unroll
    for (int t = 0; t < 2; ++t) {
      int chunk = wave * 2 + t;           // 0..7 -> 16 rows each
      int row = chunk * 16 + srow;
      gload_lds16(A + (m0 + row) * K + k0 + scol, (char*)As + chunk * 1024);
      gload_lds16(W + (n0 + row) * K + k0 + scol, (char*)Bs + chunk * 1024);
    }
    __syncthreads();  // staged data visible (vmcnt drained by barrier)

    bf16x8 af[4], bfr[4];
#pragma unroll
    for (int i = 0; i < 4; ++i)
      af[i] = *(const bf16x8*)(As + (wr + i * 16 + l15) * 32 + g * 8);
#pragma unroll
    for (int i = 0; i < 4; ++i)
      bfr[i] = *(const bf16x8*)(Bs + (wc + i * 16 + l15) * 32 + g * 8);
#pragma unroll
    for (int mi = 0; mi < 4; ++mi)
#pragma unroll
      for (int ni = 0; ni < 4; ++ni)
        acc[mi][ni] = MFMA16x16x32(af[mi], bfr[ni], acc[mi][ni]);
  }

  // epilogue: D row = (lane>>4)*4 + r, col = lane&15 (m89-verified layout)
#pragma unroll
  for (int ni = 0; ni < 4; ++ni) {
    long col = n0 + wc + ni * 16 + l15;
    float bv = bias[col];
#pragma unroll
    for (int mi = 0; mi < 4; ++mi) {
#pragma unroll
      for (int r = 0; r < 4; ++r) {
        long row = m0 + wr + mi * 16 + g * 4 + r;
        float v = acc[mi][ni][r] + bv;
        if (OUT_KIND == 0)
          ((bf16_t*)out)[row * N + col] = (bf16_t)v;
        else
          ((float*)out)[row * N + col] = v;
      }
    }
  }
}

// ---------------- Flash attention ----------------
// grid: (16 q-blocks of 128, 32 b*h). block: 256 threads = 4 waves, each wave 32 q-rows.
// KV tile = 64. K in LDS XOR-swizzled ((key&7)<<4, via pre-swizzled global src).
// V in LDS transposed [d][key] with swizzle ((d>>3)&7)<<4. P via per-wave LDS round-trip.
__global__ __launch_bounds__(256, 2) void attn_fwd(
    const bf16_t* __restrict__ Qm, const bf16_t* __restrict__ Km,
    const bf16_t* __restrict__ Vm, const float* __restrict__ mask,
    bf16_t* __restrict__ ctx) {
  constexpr int S = 2048, Hs = 1024;
  const int qb = blockIdx.x;   // 0..15
  const int bh = blockIdx.y;   // 0..31
  const int b = bh >> 4, h = bh & 15;
  const int tid = threadIdx.x;
  const int wave = tid >> 6, lane = tid & 63;
  const int g = lane >> 4, l15 = lane & 15;

  __shared__ bf16_t Ks[64 * 64];      // [key][d], swizzled
  __shared__ bf16_t Vt[64 * 64];      // [d][key], swizzled
  __shared__ bf16_t Ps[4][32 * 64];   // per-wave P [q][key], swizzled

  const bf16_t* Qbase = Qm + (long)(b * S + qb * 128 + wave * 32) * Hs + h * 64;
  const char* Kbase = (const char*)(Km + (long)b * S * Hs + h * 64);
  const bf16_t* Vbase = Vm + (long)b * S * Hs + h * 64;
  const float* mrow = mask + b * S;

  // Q fragments: A-operand, row=q (lane&15), k=d
  bf16x8 qa[2][2];
#pragma unroll
  for (int qf = 0; qf < 2; ++qf)
#pragma unroll
    for (int df = 0; df < 2; ++df)
      qa[qf][df] = *(const bf16x8*)(Qbase + (long)(qf * 16 + l15) * Hs + df * 32 + g * 8);

  f32x4 acc[2][4] = {};
  float mrun[2][4], lrun[2][4];
#pragma unroll
  for (int qf = 0; qf < 2; ++qf)
#pragma unroll
    for (int r = 0; r < 4; ++r) { mrun[qf][r] = -1e30f; lrun[qf][r] = 0.0f; }

  const int vkey_in = lane >> 3;     // 0..7
  const int vd0 = (lane & 7) * 8;    // 0..56

  for (int kb = 0; kb < 32; ++kb) {
    __syncthreads();  // all waves done reading Ks/Vt of previous tile
    // ---- stage K via global_load_lds, source pre-swizzled (m173 pattern) ----
#pragma unroll
    for (int t = 0; t < 2; ++t) {
      int chunk = wave * 2 + t;                 // 8 rows (1024B) per chunk
      int row = chunk * 8 + (lane >> 3);        // key within tile
      int slot = (lane & 7) ^ (lane >> 3);      // 16B slot XOR (row&7)
      gload_lds16(Kbase + (long)(kb * 64 + row) * (Hs * 2) + slot * 16,
                  (char*)Ks + chunk * 1024);
    }
    // ---- stage V transposed (reg-staged) ----
    int4 vv[2];
#pragma unroll
    for (int t = 0; t < 2; ++t) {
      int key = kb * 64 + (wave * 2 + t) * 8 + vkey_in;
      vv[t] = *(const int4*)(Vbase + (long)key * Hs + vd0);
    }
#pragma unroll
    for (int t = 0; t < 2; ++t) {
      int key = (wave * 2 + t) * 8 + vkey_in;  // within tile
      const u16* vr = (const u16*)&vv[t];
#pragma unroll
      for (int j = 0; j < 8; ++j) {
        int d = vd0 + j;                       // d>>3 == lane&7
        int off = d * 128 + ((key * 2) ^ ((lane & 7) << 4));
        *(u16*)((char*)Vt + off) = vr[j];
      }
    }
    __syncthreads();

    // ---- K B-fragments: col=key (lane&15), k=d ----
    bf16x8 kf[4][2];
#pragma unroll
    for (int kb4 = 0; kb4 < 4; ++kb4) {
      int key = kb4 * 16 + l15;
      int sw = (key & 7) << 4;
#pragma unroll
      for (int df = 0; df < 2; ++df)
        kf[kb4][df] = *(const bf16x8*)((const char*)Ks + key * 128 + ((df * 64 + g * 16) ^ sw));
    }
    // ---- scores: S[q][key], D layout col=key, row=q ----
    f32x4 sc[2][4];
#pragma unroll
    for (int qf = 0; qf < 2; ++qf)
#pragma unroll
      for (int kb4 = 0; kb4 < 4; ++kb4) {
        f32x4 t = {};
        t = MFMA16x16x32(qa[qf][0], kf[kb4][0], t);
        t = MFMA16x16x32(qa[qf][1], kf[kb4][1], t);
        sc[qf][kb4] = t;
      }
    float mv[4];
#pragma unroll
    for (int kb4 = 0; kb4 < 4; ++kb4) mv[kb4] = mrow[kb * 64 + kb4 * 16 + l15];

#pragma unroll
    for (int qf = 0; qf < 2; ++qf) {
      float pm[4];
#pragma unroll
      for (int r = 0; r < 4; ++r) {
#pragma unroll
        for (int kb4 = 0; kb4 < 4; ++kb4)
          sc[qf][kb4][r] = sc[qf][kb4][r] * 0.125f + mv[kb4];
        pm[r] = fmaxf(fmaxf(sc[qf][0][r], sc[qf][1][r]), fmaxf(sc[qf][2][r], sc[qf][3][r]));
      }
#pragma unroll
      for (int off = 1; off < 16; off <<= 1)
#pragma unroll
        for (int r = 0; r < 4; ++r)
          pm[r] = fmaxf(pm[r], __shfl_xor(pm[r], off, 64));
#pragma unroll
      for (int r = 0; r < 4; ++r) {
        float mnew = fmaxf(mrun[qf][r], pm[r]);
        float fct = __expf(mrun[qf][r] - mnew);
        mrun[qf][r] = mnew;
        lrun[qf][r] *= fct;
#pragma unroll
        for (int db = 0; db < 4; ++db) acc[qf][db][r] *= fct;
        float rs = 0.0f;
#pragma unroll
        for (int kb4 = 0; kb4 < 4; ++kb4) {
          float p = __expf(sc[qf][kb4][r] - mnew);
          sc[qf][kb4][r] = p;
          rs += p;
        }
#pragma unroll
        for (int off = 1; off < 16; off <<= 1) rs += __shfl_xor(rs, off, 64);
        lrun[qf][r] += rs;
      }
      // ---- write P (bf16) to per-wave LDS, [q][key] with ((q&7)<<4) XOR ----
#pragma unroll
      for (int kb4 = 0; kb4 < 4; ++kb4) {
        int key2 = (kb4 * 16 + l15) * 2;
#pragma unroll
        for (int r = 0; r < 4; ++r) {
          int q = qf * 16 + g * 4 + r;
          *(u16*)((char*)Ps[wave] + q * 128 + (key2 ^ ((q & 7) << 4))) =
              bits_of((bf16_t)sc[qf][kb4][r]);
        }
      }
    }
    // ---- V B-fragments from transposed tile: col=d (lane&15), k=key ----
    bf16x8 vf[4][2];
#pragma unroll
    for (int db = 0; db < 4; ++db) {
      int d = db * 16 + l15;
      int sw = ((d >> 3) & 7) << 4;
#pragma unroll
      for (int kf2 = 0; kf2 < 2; ++kf2)
        vf[db][kf2] = *(const bf16x8*)((const char*)Vt + d * 128 + ((kf2 * 64 + g * 16) ^ sw));
    }
    // ---- PV: A = P (row=q, k=key) ----
#pragma unroll
    for (int qf = 0; qf < 2; ++qf) {
      int q = qf * 16 + l15;
      int sw = (q & 7) << 4;
      bf16x8 pa[2];
#pragma unroll
      for (int kf2 = 0; kf2 < 2; ++kf2)
        pa[kf2] = *(const bf16x8*)((const char*)Ps[wave] + q * 128 + ((kf2 * 64 + g * 16) ^ sw));
#pragma unroll
      for (int db = 0; db < 4; ++db) {
        acc[qf][db] = MFMA16x16x32(pa[0], vf[db][0], acc[qf][db]);
        acc[qf][db] = MFMA16x16x32(pa[1], vf[db][1], acc[qf][db]);
      }
    }
  }

  // ---- epilogue: divide by l, write ctx bf16 [b*S+s][h*64+d] ----
  const long s0 = (long)(b * S + qb * 128 + wave * 32);
#pragma unroll
  for (int qf = 0; qf < 2; ++qf)
#pragma unroll
    for (int db = 0; db < 4; ++db)
#pragma unroll
      for (int r = 0; r < 4; ++r) {
        float v = acc[qf][db][r] / lrun[qf][r];
        ctx[(s0 + qf * 16 + g * 4 + r) * Hs + h * 64 + db * 16 + l15] = (bf16_t)v;
      }
}

// ---------------- launcher ----------------
extern "C" void kernel_launch(void* const* d_in, const int* in_sizes, int n_in,
                              void* d_out, int out_size, void* d_ws, size_t ws_size,
                              hipStream_t stream) {
  (void)in_sizes; (void)n_in; (void)out_size; (void)ws_size;
  const float* X  = (const float*)d_in[0];
  const float* mask = (const float*)d_in[1];
  const float* Wq = (const float*)d_in[2];
  const float* bq = (const float*)d_in[3];
  const float* Wk = (const float*)d_in[4];
  const float* bk = (const float*)d_in[5];
  const float* Wv = (const float*)d_in[6];
  const float* bv = (const float*)d_in[7];
  const float* Wo = (const float*)d_in[8];
  const float* bo = (const float*)d_in[9];

  char* ws = (char*)d_ws;
  bf16_t* Xb  = (bf16_t*)(ws + 0);          // 8.39 MB
  bf16_t* Wqb = (bf16_t*)(ws + 8388608);    // 2.10 MB
  bf16_t* Wkb = (bf16_t*)(ws + 10485760);
  bf16_t* Wvb = (bf16_t*)(ws + 12582912);
  bf16_t* Wob = (bf16_t*)(ws + 14680064);
  bf16_t* Qb  = (bf16_t*)(ws + 16777216);   // 8.39 MB each
  bf16_t* Kb  = (bf16_t*)(ws + 25165824);
  bf16_t* Vb  = (bf16_t*)(ws + 33554432);
  bf16_t* Cb  = (bf16_t*)(ws + 41943040);   // ctx

  // converts
  cvt_f32_bf16<<<4096, 256, 0, stream>>>((const float4*)X,  (ushort4*)Xb,  1048576);
  cvt_f32_bf16<<<1024, 256, 0, stream>>>((const float4*)Wq, (ushort4*)Wqb, 262144);
  cvt_f32_bf16<<<1024, 256, 0, stream>>>((const float4*)Wk, (ushort4*)Wkb, 262144);
  cvt_f32_bf16<<<1024, 256, 0, stream>>>((const float4*)Wv, (ushort4*)Wvb, 262144);
  cvt_f32_bf16<<<1024, 256, 0, stream>>>((const float4*)Wo, (ushort4*)Wob, 262144);

  // QKV projections (one launch, z = 0/1/2)
  dim3 gq(32, 8, 3);
  gemm_bt<0><<<gq, 256, 0, stream>>>(Xb, Wqb, Wkb, Wvb, bq, bk, bv, Qb, Kb, Vb);

  // attention
  dim3 ga(16, 32, 1);
  attn_fwd<<<ga, 256, 0, stream>>>(Qb, Kb, Vb, mask, Cb);

  // output projection -> f32 d_out
  dim3 go(32, 8, 1);
  gemm_bt<1><<<go, 256, 0, stream>>>(Cb, Wob, Wob, Wob, bo, bo, bo, d_out, d_out, d_out);
}

// Round 2
// 140.845 us; speedup vs baseline: 1.3496x; 1.3496x over previous
//
#include <hip/hip_runtime.h>
#include <hip/hip_bf16.h>

typedef __bf16 bf16_t;
typedef __bf16 bf16x8 __attribute__((ext_vector_type(8)));
typedef float f32x4 __attribute__((ext_vector_type(4)));
typedef float f32x16 __attribute__((ext_vector_type(16)));
typedef unsigned short u16;

#define DEVI __device__ __forceinline__
#define MFMA16x16x32(A, B, C) __builtin_amdgcn_mfma_f32_16x16x32_bf16(A, B, C, 0, 0, 0)
#define MFMA32x32x16(A, B, C) __builtin_amdgcn_mfma_f32_32x32x16_bf16(A, B, C, 0, 0, 0)

DEVI void gload_lds16(const void* g, void* l) {
  __builtin_amdgcn_global_load_lds(
      (const __attribute__((address_space(1))) void*)g,
      (__attribute__((address_space(3))) void*)l, 16, 0, 0);
}

DEVI u16 bits_of(bf16_t x) { return __builtin_bit_cast(u16, x); }

DEVI unsigned pk2(float lo, float hi) {
  return (unsigned)bits_of((bf16_t)lo) | ((unsigned)bits_of((bf16_t)hi) << 16);
}

DEVI bf16x8 mk_frag(unsigned s0, unsigned s1, unsigned s2, unsigned s3) {
  int4 t;
  t.x = (int)s0; t.y = (int)s1; t.z = (int)s2; t.w = (int)s3;
  return __builtin_bit_cast(bf16x8, t);
}

// ---------------- fp32 -> bf16 conversion (vectorized) ----------------
__global__ void cvt_f32_bf16(const float4* __restrict__ in, ushort4* __restrict__ out, int n4) {
  int i = blockIdx.x * 256 + threadIdx.x;
  if (i < n4) {
    float4 v = in[i];
    ushort4 o;
    o.x = bits_of((bf16_t)v.x);
    o.y = bits_of((bf16_t)v.y);
    o.z = bits_of((bf16_t)v.z);
    o.w = bits_of((bf16_t)v.w);
    out[i] = o;
  }
}

// ---------------- GEMM: out[m][n] = sum_k A[m][k] * W[n][k] + bias[n] ----------------
template <int OUT_KIND>
__global__ __launch_bounds__(256, 3) void gemm_bt(
    const bf16_t* __restrict__ A,
    const bf16_t* __restrict__ W0, const bf16_t* __restrict__ W1, const bf16_t* __restrict__ W2,
    const float* __restrict__ b0, const float* __restrict__ b1, const float* __restrict__ b2,
    void* o0, void* o1, void* o2) {
  constexpr int K = 1024, N = 1024;
  const int z = blockIdx.z;
  const bf16_t* W = (z == 0) ? W0 : ((z == 1) ? W1 : W2);
  const float* bias = (z == 0) ? b0 : ((z == 1) ? b1 : b2);
  void* out = (z == 0) ? o0 : ((z == 1) ? o1 : o2);

  __shared__ bf16_t As[128 * 32];
  __shared__ bf16_t Bs[128 * 32];

  const int tid = threadIdx.x;
  const int wave = tid >> 6, lane = tid & 63;
  const int g = lane >> 4, l15 = lane & 15;
  const long m0 = (long)blockIdx.x * 128;
  const long n0 = (long)blockIdx.y * 128;

  const int srow = lane >> 2;
  const int scol = (lane & 3) * 8;

  const int wr = (wave >> 1) * 64;
  const int wc = (wave & 1) * 64;

  f32x4 acc[4][4] = {};

  for (int k0 = 0; k0 < K; k0 += 32) {
    __syncthreads();
#pragma unroll
    for (int t = 0; t < 2; ++t) {
      int chunk = wave * 2 + t;
      int row = chunk * 16 + srow;
      gload_lds16(A + (m0 + row) * K + k0 + scol, (char*)As + chunk * 1024);
      gload_lds16(W + (n0 + row) * K + k0 + scol, (char*)Bs + chunk * 1024);
    }
    __syncthreads();

    bf16x8 af[4], bfr[4];
#pragma unroll
    for (int i = 0; i < 4; ++i)
      af[i] = *(const bf16x8*)(As + (wr + i * 16 + l15) * 32 + g * 8);
#pragma unroll
    for (int i = 0; i < 4; ++i)
      bfr[i] = *(const bf16x8*)(Bs + (wc + i * 16 + l15) * 32 + g * 8);
#pragma unroll
    for (int mi = 0; mi < 4; ++mi)
#pragma unroll
      for (int ni = 0; ni < 4; ++ni)
        acc[mi][ni] = MFMA16x16x32(af[mi], bfr[ni], acc[mi][ni]);
  }

#pragma unroll
  for (int ni = 0; ni < 4; ++ni) {
    long col = n0 + wc + ni * 16 + l15;
    float bv = bias[col];
#pragma unroll
    for (int mi = 0; mi < 4; ++mi) {
#pragma unroll
      for (int r = 0; r < 4; ++r) {
        long row = m0 + wr + mi * 16 + g * 4 + r;
        float v = acc[mi][ni][r] + bv;
        if (OUT_KIND == 0)
          ((bf16_t*)out)[row * N + col] = (bf16_t)v;
        else
          ((float*)out)[row * N + col] = v;
      }
    }
  }
}

// ---------------- Flash attention, swapped 32x32 (m214 structure) ----------------
// grid (32 qblocks of 64 q, 32 b*h), block = 128 threads (2 waves, 32 q each).
// QK^T swapped: D[key][q] = mfma(A=K, B=Q)  -> per-lane row slice, in-register softmax.
// PV swapped:   D2[d][q]  = mfma(A=V^T, B=P^T); P^T fragments built via pack+permlane32_swap.
// K: global_load_lds w/ pre-swizzled source, double-buffered. V: reg-staged transposed, b64 writes.
__global__ __launch_bounds__(128, 2) void attn_fwd2(
    const bf16_t* __restrict__ Qm, const bf16_t* __restrict__ Km,
    const bf16_t* __restrict__ Vm, const float* __restrict__ mask,
    bf16_t* __restrict__ ctx) {
  constexpr int S = 2048, Hs = 1024;
  // bijective XCD swizzle: 1024 blocks, 128/XCD, 4 consecutive bh per XCD (K/V 2MB <= L2)
  int id = blockIdx.y * 32 + blockIdx.x;
  int swz = ((id & 7) << 7) | (id >> 3);
  const int qb = swz & 31;
  const int bh = swz >> 5;
  const int b = bh >> 4, h = bh & 15;

  const int tid = threadIdx.x;
  const int wave = tid >> 6, lane = tid & 63;
  const int l31 = lane & 31, hi = lane >> 5;

  __shared__ bf16_t Kb_[2][64 * 64];   // [key][d], 16B-slot XOR swizzled by (key&7)
  __shared__ bf16_t Vb_[2][64 * 64];   // [d][key], 16B-slot XOR swizzled by (d&7)
  __shared__ float Ms[2048];

  const char* Kg = (const char*)(Km + ((long)b * S) * Hs + h * 64);
  const bf16_t* Vg = Vm + ((long)b * S) * Hs + h * 64;
  const float* mrow = mask + b * S;

  // hoisted Q B-fragments: col=q=l31, k-slot d = ks*16 + hi*8 + j
  const long qrow = (long)b * S + qb * 64 + wave * 32 + l31;
  const bf16_t* Qr = Qm + qrow * Hs + h * 64 + hi * 8;
  bf16x8 qB[4];
#pragma unroll
  for (int ks = 0; ks < 4; ++ks) qB[ks] = *(const bf16x8*)(Qr + ks * 16);

  // V staging assignment: thread covers keys 4ka..4ka+3  x  d dq*8..dq*8+7
  const int ka = tid & 15, dq = tid >> 4;
  const bf16_t* Vsrc0 = Vg + (long)(4 * ka) * Hs + dq * 8;

  // K staging: per wave 4 chunks of 1024B (8 rows each), pre-swizzled global source
  const int krow_in8 = lane >> 3;
  const int kslot = (lane & 7) ^ krow_in8;

  // ---- prologue: mask + tile 0 ----
#pragma unroll
  for (int c = 0; c < 4; ++c) {
    int ch = wave * 4 + c;
    gload_lds16((const char*)mrow + ch * 1024 + lane * 16, (char*)Ms + ch * 1024);
  }
#pragma unroll
  for (int c = 0; c < 4; ++c) {
    int ch = wave * 4 + c;
    gload_lds16(Kg + (long)(ch * 8 + krow_in8) * (Hs * 2) + kslot * 16,
                (char*)Kb_[0] + ch * 1024);
  }
  int4 v0 = *(const int4*)(Vsrc0);
  int4 v1 = *(const int4*)(Vsrc0 + Hs);
  int4 v2 = *(const int4*)(Vsrc0 + 2 * Hs);
  int4 v3 = *(const int4*)(Vsrc0 + 3 * Hs);
  {
    const u16* p0 = (const u16*)&v0; const u16* p1 = (const u16*)&v1;
    const u16* p2 = (const u16*)&v2; const u16* p3 = (const u16*)&v3;
#pragma unroll
    for (int j = 0; j < 8; ++j) {
      int d = dq * 8 + j;
      int2 w;
      w.x = (int)((unsigned)p0[j] | ((unsigned)p1[j] << 16));
      w.y = (int)((unsigned)p2[j] | ((unsigned)p3[j] << 16));
      *(int2*)((char*)Vb_[0] + d * 128 + ((8 * ka) ^ (j << 4))) = w;
    }
  }
  __syncthreads();

  f32x16 acc0 = {}, acc1 = {};
  float mrun = -1e30f, lrun = 0.0f;

  for (int t = 0; t < 32; ++t) {
    const int cur = t & 1;
    const char* kb_c = (const char*)Kb_[cur];
    const char* vb_c = (const char*)Vb_[cur];

    // issue next-tile loads (V first so the V-write's waitcnt leaves K gloads in flight)
    if (t < 31) {
      const bf16_t* Vs = Vsrc0 + (long)((t + 1) * 64) * Hs;
      v0 = *(const int4*)(Vs);
      v1 = *(const int4*)(Vs + Hs);
      v2 = *(const int4*)(Vs + 2 * Hs);
      v3 = *(const int4*)(Vs + 3 * Hs);
#pragma unroll
      for (int c = 0; c < 4; ++c) {
        int ch = wave * 4 + c;
        gload_lds16(Kg + (long)((t + 1) * 64 + ch * 8 + krow_in8) * (Hs * 2) + kslot * 16,
                    (char*)Kb_[cur ^ 1] + ch * 1024);
      }
    }

    // ---- QK^T: D[key][q], subtiles st=0,1 (keys st*32 + 0..31) ----
    f32x16 sc0 = {}, sc1 = {};
#pragma unroll
    for (int ks = 0; ks < 4; ++ks) {
      bf16x8 kf = *(const bf16x8*)(kb_c + l31 * 128 + (((2 * ks + hi) * 16) ^ ((l31 & 7) << 4)));
      sc0 = MFMA32x32x16(kf, qB[ks], sc0);
    }
#pragma unroll
    for (int ks = 0; ks < 4; ++ks) {
      int row = 32 + l31;
      bf16x8 kf = *(const bf16x8*)(kb_c + row * 128 + (((2 * ks + hi) * 16) ^ ((row & 7) << 4)));
      sc1 = MFMA32x32x16(kf, qB[ks], sc1);
    }

    // ---- scale + mask + online softmax (in-register; key = t*64+st*32+ (r&3)+8*(r>>2)+4*hi) ----
    const float* mbase = Ms + t * 64;
    float mt = -1e30f;
#pragma unroll
    for (int st = 0; st < 2; ++st) {
      f32x16& s = st ? sc1 : sc0;
#pragma unroll
      for (int rg = 0; rg < 4; ++rg) {
        f32x4 mk = *(const f32x4*)(mbase + st * 32 + rg * 8 + hi * 4);
#pragma unroll
        for (int i = 0; i < 4; ++i) {
          float v = s[rg * 4 + i] * 0.125f + mk[i];
          s[rg * 4 + i] = v;
          mt = fmaxf(mt, v);
        }
      }
    }
    mt = fmaxf(mt, __shfl_xor(mt, 32, 64));

    bool defer = __all(mt <= mrun + 8.0f);
    if (!defer) {
      float mnew = fmaxf(mrun, mt);
      float fct = __expf(mrun - mnew);
      lrun *= fct;
#pragma unroll
      for (int i = 0; i < 16; ++i) { acc0[i] *= fct; acc1[i] *= fct; }
      mrun = mnew;
    }
    float ls = 0.0f;
#pragma unroll
    for (int st = 0; st < 2; ++st) {
      f32x16& s = st ? sc1 : sc0;
#pragma unroll
      for (int i = 0; i < 16; ++i) {
        float p = __expf(s[i] - mrun);
        s[i] = p;
        ls += p;
      }
    }
    ls += __shfl_xor(ls, 32, 64);
    lrun += ls;

    // ---- write next V tile (loads have had QK^T+softmax to land; K gloads stay in flight) ----
    if (t < 31) {
      const u16* p0 = (const u16*)&v0; const u16* p1 = (const u16*)&v1;
      const u16* p2 = (const u16*)&v2; const u16* p3 = (const u16*)&v3;
      char* vb_n = (char*)Vb_[cur ^ 1];
#pragma unroll
      for (int j = 0; j < 8; ++j) {
        int d = dq * 8 + j;
        int2 w;
        w.x = (int)((unsigned)p0[j] | ((unsigned)p1[j] << 16));
        w.y = (int)((unsigned)p2[j] | ((unsigned)p3[j] << 16));
        *(int2*)(vb_n + d * 128 + ((8 * ka) ^ (j << 4))) = w;
      }
    }

    // ---- P^T fragments (pack + permlane32_swap) and PV ----
#pragma unroll
    for (int st = 0; st < 2; ++st) {
      f32x16& s = st ? sc1 : sc0;
      unsigned a0 = pk2(s[0], s[1]),   b0 = pk2(s[4], s[5]);
      unsigned a1 = pk2(s[2], s[3]),   b1 = pk2(s[6], s[7]);
      unsigned a2 = pk2(s[8], s[9]),   b2 = pk2(s[12], s[13]);
      unsigned a3 = pk2(s[10], s[11]), b3 = pk2(s[14], s[15]);
      asm("v_permlane32_swap_b32 %0, %1" : "+v"(a0), "+v"(b0));
      asm("v_permlane32_swap_b32 %0, %1" : "+v"(a1), "+v"(b1));
      asm("v_permlane32_swap_b32 %0, %1" : "+v"(a2), "+v"(b2));
      asm("v_permlane32_swap_b32 %0, %1" : "+v"(a3), "+v"(b3));
      bf16x8 pb0 = mk_frag(a0, a1, b0, b1);   // keys st*32 + 0..15
      bf16x8 pb1 = mk_frag(a2, a3, b2, b3);   // keys st*32 + 16..31
#pragma unroll
      for (int ks2 = 0; ks2 < 2; ++ks2) {
        bf16x8 pb = ks2 ? pb1 : pb0;
        int slot = st * 4 + ks2 * 2 + hi;   // 16B col slot in Vb row
#pragma unroll
        for (int dh = 0; dh < 2; ++dh) {
          int d = dh * 32 + l31;
          bf16x8 va = *(const bf16x8*)(vb_c + d * 128 + ((slot * 16) ^ ((d & 7) << 4)));
          if (dh == 0) acc0 = MFMA32x32x16(va, pb, acc0);
          else         acc1 = MFMA32x32x16(va, pb, acc1);
        }
      }
    }
    __syncthreads();
  }

  // ---- epilogue: D2 col=q=l31, row d = dh*32 + (r&3)+8*(r>>2)+4*hi ----
  float inv = 1.0f / lrun;
  bf16_t* cb = ctx + qrow * Hs + h * 64;
#pragma unroll
  for (int dh = 0; dh < 2; ++dh) {
    f32x16& a = dh ? acc1 : acc0;
#pragma unroll
    for (int rg = 0; rg < 4; ++rg) {
      ushort4 o;
      o.x = bits_of((bf16_t)(a[rg * 4 + 0] * inv));
      o.y = bits_of((bf16_t)(a[rg * 4 + 1] * inv));
      o.z = bits_of((bf16_t)(a[rg * 4 + 2] * inv));
      o.w = bits_of((bf16_t)(a[rg * 4 + 3] * inv));
      *(ushort4*)(cb + dh * 32 + rg * 8 + hi * 4) = o;
    }
  }
}

// ---------------- launcher ----------------
extern "C" void kernel_launch(void* const* d_in, const int* in_sizes, int n_in,
                              void* d_out, int out_size, void* d_ws, size_t ws_size,
                              hipStream_t stream) {
  (void)in_sizes; (void)n_in; (void)out_size; (void)ws_size;
  const float* X  = (const float*)d_in[0];
  const float* mask = (const float*)d_in[1];
  const float* Wq = (const float*)d_in[2];
  const float* bq = (const float*)d_in[3];
  const float* Wk = (const float*)d_in[4];
  const float* bk = (const float*)d_in[5];
  const float* Wv = (const float*)d_in[6];
  const float* bv = (const float*)d_in[7];
  const float* Wo = (const float*)d_in[8];
  const float* bo = (const float*)d_in[9];

  char* ws = (char*)d_ws;
  bf16_t* Xb  = (bf16_t*)(ws + 0);
  bf16_t* Wqb = (bf16_t*)(ws + 8388608);
  bf16_t* Wkb = (bf16_t*)(ws + 10485760);
  bf16_t* Wvb = (bf16_t*)(ws + 12582912);
  bf16_t* Wob = (bf16_t*)(ws + 14680064);
  bf16_t* Qb  = (bf16_t*)(ws + 16777216);
  bf16_t* Kb  = (bf16_t*)(ws + 25165824);
  bf16_t* Vb  = (bf16_t*)(ws + 33554432);
  bf16_t* Cb  = (bf16_t*)(ws + 41943040);

  cvt_f32_bf16<<<4096, 256, 0, stream>>>((const float4*)X,  (ushort4*)Xb,  1048576);
  cvt_f32_bf16<<<1024, 256, 0, stream>>>((const float4*)Wq, (ushort4*)Wqb, 262144);
  cvt_f32_bf16<<<1024, 256, 0, stream>>>((const float4*)Wk, (ushort4*)Wkb, 262144);
  cvt_f32_bf16<<<1024, 256, 0, stream>>>((const float4*)Wv, (ushort4*)Wvb, 262144);
  cvt_f32_bf16<<<1024, 256, 0, stream>>>((const float4*)Wo, (ushort4*)Wob, 262144);

  dim3 gq(32, 8, 3);
  gemm_bt<0><<<gq, 256, 0, stream>>>(Xb, Wqb, Wkb, Wvb, bq, bk, bv, Qb, Kb, Vb);

  dim3 ga(32, 32, 1);
  attn_fwd2<<<ga, 128, 0, stream>>>(Qb, Kb, Vb, mask, Cb);

  dim3 go(32, 8, 1);
  gemm_bt<1><<<go, 256, 0, stream>>>(Cb, Wob, Wob, Wob, bo, bo, bo, d_out, d_out, d_out);
}